// Round 3
// baseline (205.831 us; speedup 1.0000x reference)
//
#include <hip/hip_runtime.h>
#include <math.h>

#define B_ 4
#define S_ 2048
#define D_ 512
#define H_ 8
#define HD_ 64
#define RL_ 64
#define LN_EPS 1e-5f
#define SLOPE 0.01f
#define LOG2E 1.4426950408889634f

typedef __attribute__((ext_vector_type(8))) __bf16 bf16x8;
typedef __attribute__((ext_vector_type(4))) float f32x4;

__device__ __forceinline__ float leaky(float x) { return x >= 0.f ? x : SLOPE * x; }

// float -> bf16 (RNE)
__device__ __forceinline__ ushort f2bf(float f) {
    union { float f; unsigned u; } v; v.f = f;
    unsigned r = v.u + 0x7fffu + ((v.u >> 16) & 1u);
    return (ushort)(r >> 16);
}
__device__ __forceinline__ unsigned fbits(float f) {
    union { float f; unsigned u; } v; v.f = f; return v.u;
}

__device__ __forceinline__ void g2lds16(const void* g, void* l) {
    __builtin_amdgcn_global_load_lds(
        (const __attribute__((address_space(1))) void*)(uintptr_t)g,
        (__attribute__((address_space(3))) void*)(uintptr_t)l, 16, 0, 0);
}

// ---------------------------------------------------------------------------
// prep (merged): grid 4752
// ---------------------------------------------------------------------------
__global__ __launch_bounds__(256) void prep(
    const float* __restrict__ h, const float* __restrict__ rh,
    const float* __restrict__ Wr, const float* __restrict__ Wf,
    const float* __restrict__ Wrs, const float* __restrict__ Wrt,
    ushort* __restrict__ hb, ushort* __restrict__ rhb,
    ushort* __restrict__ WrT, ushort* __restrict__ WfT,
    ushort* __restrict__ WrsT, ushort* __restrict__ WrtT)
{
    const int bx = blockIdx.x, tid = threadIdx.x;
    if (bx < 4608) {
        const float* in = (bx < 4096) ? h : rh;
        ushort* o = (bx < 4096) ? hb : rhb;
        const int i = (bx < 4096 ? bx : bx - 4096) * 256 + tid;
        const float4 v = ((const float4*)in)[i];
        ushort4 u; u.x = f2bf(v.x); u.y = f2bf(v.y); u.z = f2bf(v.z); u.w = f2bf(v.w);
        ((ushort4*)o)[i] = u;
        return;
    }
    __shared__ float TS[64][65];
    int t = bx - 4608;
    const float* in; ushort* out; int K, tk, tn;
    if (t < 64)       { in = Wr;  out = WrT;  K = 512; tk = t & 7; tn = t >> 3; }
    else if (t < 128) { in = Wf;  out = WfT;  K = 512; t -= 64; tk = t & 7; tn = t >> 3; }
    else if (t < 136) { in = Wrs; out = WrsT; K = 64;  tk = 0; tn = t - 128; }
    else              { in = Wrt; out = WrtT; K = 64;  tk = 0; tn = t - 136; }
    const int k0 = tk * 64, n0 = tn * 64;
    const int r = tid >> 4, c4 = (tid & 15) * 4;
    #pragma unroll
    for (int p = 0; p < 4; ++p) {
        const int row = r + 16 * p;
        const float4 v = *(const float4*)(in + (size_t)(k0 + row) * 512 + n0 + c4);
        TS[row][c4] = v.x; TS[row][c4 + 1] = v.y;
        TS[row][c4 + 2] = v.z; TS[row][c4 + 3] = v.w;
    }
    __syncthreads();
    #pragma unroll
    for (int p = 0; p < 4; ++p) {
        const int nn = r + 16 * p;
        ushort4 o;
        o.x = f2bf(TS[c4 + 0][nn]); o.y = f2bf(TS[c4 + 1][nn]);
        o.z = f2bf(TS[c4 + 2][nn]); o.w = f2bf(TS[c4 + 3][nn]);
        *(ushort4*)(out + (size_t)(n0 + nn) * K + k0 + c4) = o;
    }
}

// ---------------------------------------------------------------------------
// proj (fused): grid (128,4,3). z=0: fr-projection (K=512) -> frT bf16 + sr;
// z=1: rk (K=64, xLOG2E); z=2: rq (K=64).
// ---------------------------------------------------------------------------
__global__ __launch_bounds__(256) void proj(
    const ushort* __restrict__ hb, const ushort* __restrict__ rhb,
    const ushort* __restrict__ WrT, const ushort* __restrict__ WrsT,
    const ushort* __restrict__ WrtT,
    ushort* __restrict__ frT, ushort* __restrict__ rkw, ushort* __restrict__ rqw,
    float* __restrict__ sred, const float* __restrict__ ar)
{
    __shared__ ushort As[2][64 * 32];
    __shared__ ushort Bs[2][128 * 32];

    const int tid = threadIdx.x;
    const int lane = tid & 63, w = tid >> 6;
    const int ln = lane & 15, quad = lane >> 4;
    const int wm = w >> 1, wn = w & 1;
    const int m0 = blockIdx.x * 64, n0 = blockIdx.y * 128;
    const int z = blockIdx.z;

    const ushort* A; const ushort* wt; ushort* co; float scl; int K;
    if (z == 0)      { A = hb;  wt = WrT;  co = frT; scl = LOG2E; K = 512; }
    else if (z == 1) { A = rhb; wt = WrsT; co = rkw; scl = LOG2E; K = 64; }
    else             { A = rhb; wt = WrtT; co = rqw; scl = 1.0f;  K = 64; }

    const int srA = tid >> 2;
    const int lchA = ((lane & 3) - (srA >> 1)) & 3;
    const ushort* AgB = A + (size_t)(m0 + srA) * K + lchA * 8;
    const int srB = w * 32 + (lane >> 2);
    const int lchB = ((lane & 3) - (srB >> 1)) & 3;
    const ushort* BgB0 = wt + (size_t)(n0 + srB) * K + lchB * 8;
    const ushort* BgB1 = BgB0 + (size_t)16 * K;
    const int aoff = tid * 8;
    const int boff = srB * 32 + (lane & 3) * 8;
    const int pc = (quad + (ln >> 1)) & 3;

    g2lds16(AgB, &As[0][aoff]);
    g2lds16(BgB0, &Bs[0][boff]);
    g2lds16(BgB1, &Bs[0][boff + 512]);

    f32x4 acc[2][4] = {};
    int buf = 0;
    for (int k0 = 0; k0 < K; k0 += 32) {
        __syncthreads();
        if (k0 + 32 < K) {
            g2lds16(AgB + k0 + 32, &As[buf ^ 1][aoff]);
            g2lds16(BgB0 + k0 + 32, &Bs[buf ^ 1][boff]);
            g2lds16(BgB1 + k0 + 32, &Bs[buf ^ 1][boff + 512]);
        }
        bf16x8 af[2], bfr[4];
        #pragma unroll
        for (int mi = 0; mi < 2; ++mi)
            af[mi] = *(const bf16x8*)&As[buf][(wm * 32 + mi * 16 + ln) * 32 + pc * 8];
        #pragma unroll
        for (int ni = 0; ni < 4; ++ni)
            bfr[ni] = *(const bf16x8*)&Bs[buf][(wn * 64 + ni * 16 + ln) * 32 + pc * 8];
        #pragma unroll
        for (int mi = 0; mi < 2; ++mi)
            #pragma unroll
            for (int ni = 0; ni < 4; ++ni)
                acc[mi][ni] = __builtin_amdgcn_mfma_f32_16x16x32_bf16(
                    af[mi], bfr[ni], acc[mi][ni], 0, 0, 0);
        buf ^= 1;
    }

    const int head = blockIdx.y * 2 + wn;
    const int b = m0 >> 11;
    const size_t bh = (size_t)b * H_ + head;
    if (z == 0) {
        #pragma unroll
        for (int mi = 0; mi < 2; ++mi) {
            const int s = (m0 & (S_ - 1)) + wm * 32 + mi * 16 + quad * 4;
            #pragma unroll
            for (int ni = 0; ni < 4; ++ni) {
                const int d = ni * 16 + ln;
                ushort4 o;
                o.x = f2bf(acc[mi][ni][0]); o.y = f2bf(acc[mi][ni][1]);
                o.z = f2bf(acc[mi][ni][2]); o.w = f2bf(acc[mi][ni][3]);
                *(ushort4*)(co + (bh * 64 + d) * S_ + s) = o;
            }
        }
        float a4[4];
        #pragma unroll
        for (int ni = 0; ni < 4; ++ni) a4[ni] = ar[ni * 16 + ln];
        #pragma unroll
        for (int mi = 0; mi < 2; ++mi) {
            const int s = (m0 & (S_ - 1)) + wm * 32 + mi * 16 + quad * 4;
            #pragma unroll
            for (int r = 0; r < 4; ++r) {
                float v = 0.f;
                #pragma unroll
                for (int ni = 0; ni < 4; ++ni)
                    v += leaky(acc[mi][ni][r]) * a4[ni];
                #pragma unroll
                for (int off = 8; off; off >>= 1) v += __shfl_xor(v, off, 16);
                if (ln == 0) sred[bh * S_ + s + r] = v * scl;
            }
        }
    } else {
        #pragma unroll
        for (int mi = 0; mi < 2; ++mi) {
            const int s = (m0 & (S_ - 1)) + wm * 32 + mi * 16 + quad * 4;
            #pragma unroll
            for (int ni = 0; ni < 4; ++ni) {
                const int d = ni * 16 + ln;
                #pragma unroll
                for (int r = 0; r < 4; ++r)
                    co[(bh * S_ + s + r) * 64 + d] = f2bf(acc[mi][ni][r] * scl);
            }
        }
    }
}

// ---------------------------------------------------------------------------
// Flash attention, bf16 MFMA. 128 q/block, 4-buffer depth-2 counted-vmcnt
// pipeline (round 2) + T15 lag-1 double-pipeline: slot i issues QK^T(i) MFMAs
// (results unused until slot i+1), then runs softmax(i-1)+PV(i-1) — the
// softmax VALU/trans work executes under the in-flight QK^T matrix-pipe time.
// FT buffer for PV(i-1) is safe: stage target (i+2)&3 != (i-1)&3.
// T5: s_setprio(1) around both MFMA clusters.
// ---------------------------------------------------------------------------
#define WAITV(N) asm volatile("s_waitcnt vmcnt(" #N ")" ::: "memory")
#define BARR()   __builtin_amdgcn_s_barrier()

__global__ __launch_bounds__(256, 2) void attn_mfma(
    const ushort* __restrict__ frT, const ushort* __restrict__ rk,
    const ushort* __restrict__ rq, const float* __restrict__ sr,
    ushort* __restrict__ hsa)
{
    __shared__ ushort RQ[4][64][64];   // 32 KB
    __shared__ ushort FT[4][64][64];   // 32 KB
    __shared__ ushort PS[8][16][64];   // 16 KB (per-wave strips, no x-wave sharing)

    const int tid = threadIdx.x;
    const int w = tid >> 6;
    const int lane = tid & 63;
    const int ln = lane & 15;
    const int quad = lane >> 4;

    // bijective XCD swizzle over 512 blocks: 64/XCD = 4 full (b,h) groups
    const int flat = blockIdx.x + 16 * (blockIdx.y + 8 * blockIdx.z); // 0..511
    const int wid = (flat & 7) * 64 + (flat >> 3);
    const int q0 = (wid & 15) * 128;
    const int h = (wid >> 4) & 7;
    const int b = wid >> 7;
    const size_t bh = (size_t)b * H_ + h;

    // A-frags (rk): q = q0 + 32w + 16qs + ln
    bf16x8 a[2][2];
    #pragma unroll
    for (int qs = 0; qs < 2; ++qs) {
        const ushort* p = rk + ((bh * S_ + q0 + 32 * w + 16 * qs + ln) << 6);
        a[qs][0] = *(const bf16x8*)(p + quad * 8);
        a[qs][1] = *(const bf16x8*)(p + 32 + quad * 8);
    }

    const ushort* rq_g = rq + (bh * S_ << 6);
    const ushort* ft_g = frT + (size_t)bh * 64 * S_;
    const float* srp = sr + bh * S_;

    // staging: block covers tile rows 0..63 (wave w: [16w,16w+16), 2x8 rows)
    const int rl = lane >> 3;
    const int pg = lane & 7;
    const int row_b = w * 16 + rl;
    const int sgF = (pg - rl) & 7;                    // FT swizzle (g+row)&7
    const int sgR0 = (pg - 4 * w - (rl >> 2)) & 7;    // RQ swizzle (g+(row>>2))&7
    const int sgR1 = (pg - 4 * w - 2 - (rl >> 2)) & 7;

    #define STAGE(BUF, t0)                                                    \
        {                                                                     \
            g2lds16(rq_g + ((size_t)((t0) + row_b) << 6) + sgR0 * 8,          \
                    &RQ[BUF][row_b][pg * 8]);                                 \
            g2lds16(rq_g + ((size_t)((t0) + row_b + 8) << 6) + sgR1 * 8,      \
                    &RQ[BUF][row_b + 8][pg * 8]);                             \
            g2lds16(ft_g + (size_t)row_b * S_ + (t0) + sgF * 8,               \
                    &FT[BUF][row_b][pg * 8]);                                 \
            g2lds16(ft_g + (size_t)(row_b + 8) * S_ + (t0) + sgF * 8,         \
                    &FT[BUF][row_b + 8][pg * 8]);                             \
        }

    // hoisted LDS read bases (+ BI*4096 selects buffer)
    const ushort* rqrA = &RQ[0][0][0] + 4 * ln * 64 + ((quad + ln) & 7) * 8;
    const ushort* rqrB = &RQ[0][0][0] + 4 * ln * 64 + ((quad + 4 + ln) & 7) * 8;
    const ushort* ftrA = &FT[0][0][0] + ln * 64 + ((quad + ln) & 7) * 8;
    const ushort* ftrB = &FT[0][0][0] + ln * 64 + ((quad + 4 + ln) & 7) * 8;
    // PS strip pointers (per qs)
    ushort* sb[2];
    sb[0] = &PS[w * 2][0][0]; sb[1] = &PS[w * 2 + 1][0][0];
    int wr_off[4];
    #pragma unroll
    for (int r = 0; r < 4; ++r) {
        const int prow = quad * 4 + r;
        wr_off[r] = prow * 64 + (((ln >> 1) + prow) & 7) * 8 + (ln & 1) * 4;
    }
    const int rd0 = ln * 64 + ((quad + ln) & 7) * 8;
    const int rd1 = ln * 64 + ((quad + 4 + ln) & 7) * 8;

    float lsum[2][4] = {};
    f32x4 ctx[2][4] = {};
    f32x4 scA[2][4], scB[2][4];

    // QK^T(half in buffer BI) -> SC; results consumed one slot later
    #define QKT(BI, SC)                                                       \
        {                                                                     \
            __builtin_amdgcn_s_setprio(1);                                    \
            _Pragma("unroll")                                                 \
            for (int jb = 0; jb < 4; ++jb) {                                  \
                const bf16x8 b0 = *(const bf16x8*)(rqrA + (BI) * 4096 + jb * 64); \
                const bf16x8 b1 = *(const bf16x8*)(rqrB + (BI) * 4096 + jb * 64); \
                _Pragma("unroll")                                             \
                for (int qs = 0; qs < 2; ++qs) {                              \
                    f32x4 tt = {0.f, 0.f, 0.f, 0.f};                          \
                    tt = __builtin_amdgcn_mfma_f32_16x16x32_bf16(a[qs][0], b0, tt, 0, 0, 0); \
                    tt = __builtin_amdgcn_mfma_f32_16x16x32_bf16(a[qs][1], b1, tt, 0, 0, 0); \
                    SC[qs][jb] = tt;                                          \
                }                                                             \
            }                                                                 \
            __builtin_amdgcn_s_setprio(0);                                    \
        }

    // softmax + PV for the PREVIOUS half: scores SC, bias SV, FT buffer BJ
    #define SMPV(SC, SV, BJ)                                                  \
        {                                                                     \
            _Pragma("unroll")                                                 \
            for (int qs = 0; qs < 2; ++qs)                                    \
                _Pragma("unroll")                                             \
                for (int r = 0; r < 4; ++r) {                                 \
                    const float p0 = __builtin_amdgcn_exp2f(SC[qs][0][r] + SV.x); \
                    const float p1 = __builtin_amdgcn_exp2f(SC[qs][1][r] + SV.y); \
                    const float p2 = __builtin_amdgcn_exp2f(SC[qs][2][r] + SV.z); \
                    const float p3 = __builtin_amdgcn_exp2f(SC[qs][3][r] + SV.w); \
                    lsum[qs][r] += (p0 + p1) + (p2 + p3);                      \
                    const unsigned lo = (fbits(p0) >> 16) | (fbits(p1) & 0xffff0000u); \
                    const unsigned hi = (fbits(p2) >> 16) | (fbits(p3) & 0xffff0000u); \
                    *(uint2*)(sb[qs] + wr_off[r]) = make_uint2(lo, hi);       \
                }                                                             \
            const bf16x8 pa00 = *(const bf16x8*)(sb[0] + rd0);                \
            const bf16x8 pa01 = *(const bf16x8*)(sb[0] + rd1);                \
            const bf16x8 pa10 = *(const bf16x8*)(sb[1] + rd0);                \
            const bf16x8 pa11 = *(const bf16x8*)(sb[1] + rd1);                \
            __builtin_amdgcn_s_setprio(1);                                    \
            _Pragma("unroll")                                                 \
            for (int jb = 0; jb < 4; ++jb) {                                  \
                const bf16x8 fb0 = *(const bf16x8*)(ftrA + (BJ) * 4096 + jb * 1024); \
                const bf16x8 fb1 = *(const bf16x8*)(ftrB + (BJ) * 4096 + jb * 1024); \
                ctx[0][jb] = __builtin_amdgcn_mfma_f32_16x16x32_bf16(pa00, fb0, ctx[0][jb], 0, 0, 0); \
                ctx[0][jb] = __builtin_amdgcn_mfma_f32_16x16x32_bf16(pa01, fb1, ctx[0][jb], 0, 0, 0); \
                ctx[1][jb] = __builtin_amdgcn_mfma_f32_16x16x32_bf16(pa10, fb0, ctx[1][jb], 0, 0, 0); \
                ctx[1][jb] = __builtin_amdgcn_mfma_f32_16x16x32_bf16(pa11, fb1, ctx[1][jb], 0, 0, 0); \
            }                                                                 \
            __builtin_amdgcn_s_setprio(0);                                    \
        }

    float4 sv0, sv1, sv2, sv3;
    // prologue: issue groups for halves 0,1
    STAGE(0, 0)   sv0 = *(const float4*)(srp + 0 + 4 * ln);
    STAGE(1, 64)  sv1 = *(const float4*)(srp + 64 + 4 * ln);

    // slot 0: QKT(0) only (nothing to finish yet)
    WAITV(5); BARR();
    STAGE(2, 128) sv2 = *(const float4*)(srp + 128 + 4 * ln);
    QKT(0, scA)
    // slot 1
    WAITV(5); BARR();
    STAGE(3, 192) sv3 = *(const float4*)(srp + 192 + 4 * ln);
    QKT(1, scB)
    SMPV(scA, sv0, 0)

    // steady state: slots 2..29 (7 x 4)
    for (int k = 0; k < 7; ++k) {
        const int t0 = k * 256;
        WAITV(5); BARR();
        STAGE(0, t0 + 256) sv0 = *(const float4*)(srp + t0 + 256 + 4 * ln);
        QKT(2, scA)
        SMPV(scB, sv1, 1)
        WAITV(5); BARR();
        STAGE(1, t0 + 320) sv1 = *(const float4*)(srp + t0 + 320 + 4 * ln);
        QKT(3, scB)
        SMPV(scA, sv2, 2)
        WAITV(5); BARR();
        STAGE(2, t0 + 384) sv2 = *(const float4*)(srp + t0 + 384 + 4 * ln);
        QKT(0, scA)
        SMPV(scB, sv3, 3)
        WAITV(5); BARR();
        STAGE(3, t0 + 448) sv3 = *(const float4*)(srp + t0 + 448 + 4 * ln);
        QKT(1, scB)
        SMPV(scA, sv0, 0)
    }
    // tail: slots 30,31 + flush (halves 30,31 staged at slots 28,29)
    WAITV(5); BARR();
    QKT(2, scA)            // half 30
    SMPV(scB, sv1, 1)      // half 29
    WAITV(0); BARR();
    QKT(3, scB)            // half 31
    SMPV(scA, sv2, 2)      // half 30
    SMPV(scB, sv3, 3)      // half 31 (flush)

    #pragma unroll
    for (int qs = 0; qs < 2; ++qs)
        #pragma unroll
        for (int r = 0; r < 4; ++r) {
            float l = lsum[qs][r];
            #pragma unroll
            for (int off = 8; off; off >>= 1) l += __shfl_xor(l, off, 16);
            const float inv = 1.f / l;
            const int q = q0 + 32 * w + 16 * qs + quad * 4 + r;
            ushort* orow = hsa + (size_t)(b * S_ + q) * D_ + h * 64;
            #pragma unroll
            for (int jb = 0; jb < 4; ++jb)
                orow[16 * jb + ln] = f2bf(ctx[qs][jb][r] * inv);
        }
}

// ---------------------------------------------------------------------------
// final projection GEMM (fp32 out), double-buffered
// ---------------------------------------------------------------------------
__global__ __launch_bounds__(256) void gemm_out(
    const ushort* __restrict__ A, const ushort* __restrict__ WT,
    float* __restrict__ C)
{
    __shared__ ushort As[2][64 * 32];
    __shared__ ushort Bs[2][128 * 32];

    const int tid = threadIdx.x;
    const int lane = tid & 63, w = tid >> 6;
    const int ln = lane & 15, quad = lane >> 4;
    const int wm = w >> 1, wn = w & 1;
    const int m0 = blockIdx.x * 64, n0 = blockIdx.y * 128;
    const int K = 512;

    const int srA = tid >> 2;
    const int lchA = ((lane & 3) - (srA >> 1)) & 3;
    const ushort* AgB = A + (size_t)(m0 + srA) * K + lchA * 8;
    const int srB = w * 32 + (lane >> 2);
    const int lchB = ((lane & 3) - (srB >> 1)) & 3;
    const ushort* BgB0 = WT + (size_t)(n0 + srB) * K + lchB * 8;
    const ushort* BgB1 = BgB0 + (size_t)16 * K;
    const int aoff = tid * 8;
    const int boff = srB * 32 + (lane & 3) * 8;
    const int pc = (quad + (ln >> 1)) & 3;

    g2lds16(AgB, &As[0][aoff]);
    g2lds16(BgB0, &Bs[0][boff]);
    g2lds16(BgB1, &Bs[0][boff + 512]);

    f32x4 acc[2][4] = {};
    int buf = 0;
    for (int k0 = 0; k0 < K; k0 += 32) {
        __syncthreads();
        if (k0 + 32 < K) {
            g2lds16(AgB + k0 + 32, &As[buf ^ 1][aoff]);
            g2lds16(BgB0 + k0 + 32, &Bs[buf ^ 1][boff]);
            g2lds16(BgB1 + k0 + 32, &Bs[buf ^ 1][boff + 512]);
        }
        bf16x8 af[2], bfr[4];
        #pragma unroll
        for (int mi = 0; mi < 2; ++mi)
            af[mi] = *(const bf16x8*)&As[buf][(wm * 32 + mi * 16 + ln) * 32 + pc * 8];
        #pragma unroll
        for (int ni = 0; ni < 4; ++ni)
            bfr[ni] = *(const bf16x8*)&Bs[buf][(wn * 64 + ni * 16 + ln) * 32 + pc * 8];
        #pragma unroll
        for (int mi = 0; mi < 2; ++mi)
            #pragma unroll
            for (int ni = 0; ni < 4; ++ni)
                acc[mi][ni] = __builtin_amdgcn_mfma_f32_16x16x32_bf16(
                    af[mi], bfr[ni], acc[mi][ni], 0, 0, 0);
        buf ^= 1;
    }

    #pragma unroll
    for (int mi = 0; mi < 2; ++mi) {
        const int row = m0 + wm * 32 + mi * 16 + quad * 4;
        #pragma unroll
        for (int ni = 0; ni < 4; ++ni) {
            const int col = n0 + wn * 64 + ni * 16 + ln;
            #pragma unroll
            for (int r = 0; r < 4; ++r)
                C[(size_t)(row + r) * 512 + col] = acc[mi][ni][r];
        }
    }
}

// ---------------------------------------------------------------------------
// LayerNorm(h + fh) * g + b
// ---------------------------------------------------------------------------
__global__ __launch_bounds__(256) void ln_kernel(
    const float* __restrict__ h, const float* __restrict__ fh,
    const float* __restrict__ g, const float* __restrict__ bb,
    float* __restrict__ out)
{
    const int row = blockIdx.x, tid = threadIdx.x;
    const float* hp = h + (size_t)row * 512;
    const float* fp = fh + (size_t)row * 512;
    const float x0 = hp[tid] + fp[tid];
    const float x1 = hp[tid + 256] + fp[tid + 256];
    __shared__ float red[4];

    float s = x0 + x1;
    #pragma unroll
    for (int off = 32; off; off >>= 1) s += __shfl_xor(s, off, 64);
    if ((tid & 63) == 0) red[tid >> 6] = s;
    __syncthreads();
    const float mu = (red[0] + red[1] + red[2] + red[3]) * (1.f / 512.f);

    const float d0 = x0 - mu, d1 = x1 - mu;
    float v = d0 * d0 + d1 * d1;
    #pragma unroll
    for (int off = 32; off; off >>= 1) v += __shfl_xor(v, off, 64);
    __syncthreads();
    if ((tid & 63) == 0) red[tid >> 6] = v;
    __syncthreads();
    const float var = (red[0] + red[1] + red[2] + red[3]) * (1.f / 512.f);
    const float inv = rsqrtf(var + LN_EPS);

    out[(size_t)row * 512 + tid] = d0 * inv * g[tid] + bb[tid];
    out[(size_t)row * 512 + tid + 256] = d1 * inv * g[tid + 256] + bb[tid + 256];
}

// ---------------------------------------------------------------------------
extern "C" void kernel_launch(void* const* d_in, const int* in_sizes, int n_in,
                              void* d_out, int out_size, void* d_ws, size_t ws_size,
                              hipStream_t stream)
{
    const float* h   = (const float*)d_in[0];
    const float* rh  = (const float*)d_in[1];
    // d_in[2] = Wl, d_in[4] = al : unused — sl cancels in softmax
    const float* Wr  = (const float*)d_in[3];
    const float* ar  = (const float*)d_in[5];
    const float* Wrs = (const float*)d_in[6];
    const float* Wrt = (const float*)d_in[7];
    const float* Wf  = (const float*)d_in[8];
    const float* lng = (const float*)d_in[9];
    const float* lnb = (const float*)d_in[10];
    float* out = (float*)d_out;
    char* wsb  = (char*)d_ws;

    const size_t MB = (size_t)1 << 20;
    ushort* hb   = (ushort*)(wsb);               //  8 MB
    ushort* rhb  = (ushort*)(wsb + 8 * MB);      //  1 MB
    ushort* WrT  = (ushort*)(wsb + 9 * MB);      // .5 MB
    ushort* WfT  = (ushort*)(wsb + 9 * MB + 512 * 1024);
    ushort* WrsT = (ushort*)(wsb + 10 * MB);     // 64 KB
    ushort* WrtT = (ushort*)(wsb + 10 * MB + 64 * 1024);
    ushort* frT  = (ushort*)(wsb + 11 * MB);     //  8 MB  [B,H,64,S]
    ushort* rkw  = (ushort*)(wsb + 19 * MB);     //  8 MB  [B,H,S,64]
    ushort* rqw  = (ushort*)(wsb + 27 * MB);     //  8 MB  [B,H,S,64]
    float*  sr   = (float*) (wsb + 35 * MB);     // .25MB  [B,H,S]
    ushort* hsab = (ushort*)(wsb + 36 * MB);     //  8 MB  [B,S,512] bf16
    float*  fh   = (float*) (wsb + 44 * MB);     // 16 MB  [B,S,512] f32

    dim3 blk(256);
    prep<<<dim3(4752), blk, 0, stream>>>(h, rh, Wr, Wf, Wrs, Wrt,
                                         hb, rhb, WrT, WfT, WrsT, WrtT);
    proj<<<dim3(128, 4, 3), blk, 0, stream>>>(hb, rhb, WrT, WrsT, WrtT,
                                              frT, rkw, rqw, sr, ar);
    // attention: 128 q/block, depth-2 counted-vmcnt + lag-1 double-pipeline
    attn_mfma<<<dim3(S_ / 128, H_, B_), blk, 0, stream>>>(frT, rkw, rqw, sr, hsab);
    gemm_out<<<dim3(128, 4), blk, 0, stream>>>(hsab, WfT, fh);
    ln_kernel<<<dim3(B_ * S_), blk, 0, stream>>>(h, fh, lng, lnb, out);
}

// Round 4
// 188.598 us; speedup vs baseline: 1.0914x; 1.0914x over previous
//
#include <hip/hip_runtime.h>
#include <math.h>

#define B_ 4
#define S_ 2048
#define D_ 512
#define H_ 8
#define HD_ 64
#define RL_ 64
#define LN_EPS 1e-5f
#define SLOPE 0.01f
#define LOG2E 1.4426950408889634f

typedef __attribute__((ext_vector_type(8))) __bf16 bf16x8;
typedef __attribute__((ext_vector_type(4))) float f32x4;

__device__ __forceinline__ float leaky(float x) { return x >= 0.f ? x : SLOPE * x; }

// float -> bf16 (RNE)
__device__ __forceinline__ ushort f2bf(float f) {
    union { float f; unsigned u; } v; v.f = f;
    unsigned r = v.u + 0x7fffu + ((v.u >> 16) & 1u);
    return (ushort)(r >> 16);
}
__device__ __forceinline__ unsigned fbits(float f) {
    union { float f; unsigned u; } v; v.f = f; return v.u;
}

__device__ __forceinline__ void g2lds16(const void* g, void* l) {
    __builtin_amdgcn_global_load_lds(
        (const __attribute__((address_space(1))) void*)(uintptr_t)g,
        (__attribute__((address_space(3))) void*)(uintptr_t)l, 16, 0, 0);
}

// ---------------------------------------------------------------------------
// prep (merged): grid 4752
// ---------------------------------------------------------------------------
__global__ __launch_bounds__(256) void prep(
    const float* __restrict__ h, const float* __restrict__ rh,
    const float* __restrict__ Wr, const float* __restrict__ Wf,
    const float* __restrict__ Wrs, const float* __restrict__ Wrt,
    ushort* __restrict__ hb, ushort* __restrict__ rhb,
    ushort* __restrict__ WrT, ushort* __restrict__ WfT,
    ushort* __restrict__ WrsT, ushort* __restrict__ WrtT)
{
    const int bx = blockIdx.x, tid = threadIdx.x;
    if (bx < 4608) {
        const float* in = (bx < 4096) ? h : rh;
        ushort* o = (bx < 4096) ? hb : rhb;
        const int i = (bx < 4096 ? bx : bx - 4096) * 256 + tid;
        const float4 v = ((const float4*)in)[i];
        ushort4 u; u.x = f2bf(v.x); u.y = f2bf(v.y); u.z = f2bf(v.z); u.w = f2bf(v.w);
        ((ushort4*)o)[i] = u;
        return;
    }
    __shared__ float TS[64][65];
    int t = bx - 4608;
    const float* in; ushort* out; int K, tk, tn;
    if (t < 64)       { in = Wr;  out = WrT;  K = 512; tk = t & 7; tn = t >> 3; }
    else if (t < 128) { in = Wf;  out = WfT;  K = 512; t -= 64; tk = t & 7; tn = t >> 3; }
    else if (t < 136) { in = Wrs; out = WrsT; K = 64;  tk = 0; tn = t - 128; }
    else              { in = Wrt; out = WrtT; K = 64;  tk = 0; tn = t - 136; }
    const int k0 = tk * 64, n0 = tn * 64;
    const int r = tid >> 4, c4 = (tid & 15) * 4;
    #pragma unroll
    for (int p = 0; p < 4; ++p) {
        const int row = r + 16 * p;
        const float4 v = *(const float4*)(in + (size_t)(k0 + row) * 512 + n0 + c4);
        TS[row][c4] = v.x; TS[row][c4 + 1] = v.y;
        TS[row][c4 + 2] = v.z; TS[row][c4 + 3] = v.w;
    }
    __syncthreads();
    #pragma unroll
    for (int p = 0; p < 4; ++p) {
        const int nn = r + 16 * p;
        ushort4 o;
        o.x = f2bf(TS[c4 + 0][nn]); o.y = f2bf(TS[c4 + 1][nn]);
        o.z = f2bf(TS[c4 + 2][nn]); o.w = f2bf(TS[c4 + 3][nn]);
        *(ushort4*)(out + (size_t)(n0 + nn) * K + k0 + c4) = o;
    }
}

// ---------------------------------------------------------------------------
// proj (fused): grid (128,4,3). z=0: fr-projection (K=512) -> frT bf16 + sr;
// z=1: rk (K=64, xLOG2E); z=2: rq (K=64).
// ---------------------------------------------------------------------------
__global__ __launch_bounds__(256) void proj(
    const ushort* __restrict__ hb, const ushort* __restrict__ rhb,
    const ushort* __restrict__ WrT, const ushort* __restrict__ WrsT,
    const ushort* __restrict__ WrtT,
    ushort* __restrict__ frT, ushort* __restrict__ rkw, ushort* __restrict__ rqw,
    float* __restrict__ sred, const float* __restrict__ ar)
{
    __shared__ ushort As[2][64 * 32];
    __shared__ ushort Bs[2][128 * 32];

    const int tid = threadIdx.x;
    const int lane = tid & 63, w = tid >> 6;
    const int ln = lane & 15, quad = lane >> 4;
    const int wm = w >> 1, wn = w & 1;
    const int m0 = blockIdx.x * 64, n0 = blockIdx.y * 128;
    const int z = blockIdx.z;

    const ushort* A; const ushort* wt; ushort* co; float scl; int K;
    if (z == 0)      { A = hb;  wt = WrT;  co = frT; scl = LOG2E; K = 512; }
    else if (z == 1) { A = rhb; wt = WrsT; co = rkw; scl = LOG2E; K = 64; }
    else             { A = rhb; wt = WrtT; co = rqw; scl = 1.0f;  K = 64; }

    const int srA = tid >> 2;
    const int lchA = ((lane & 3) - (srA >> 1)) & 3;
    const ushort* AgB = A + (size_t)(m0 + srA) * K + lchA * 8;
    const int srB = w * 32 + (lane >> 2);
    const int lchB = ((lane & 3) - (srB >> 1)) & 3;
    const ushort* BgB0 = wt + (size_t)(n0 + srB) * K + lchB * 8;
    const ushort* BgB1 = BgB0 + (size_t)16 * K;
    const int aoff = tid * 8;
    const int boff = srB * 32 + (lane & 3) * 8;
    const int pc = (quad + (ln >> 1)) & 3;

    g2lds16(AgB, &As[0][aoff]);
    g2lds16(BgB0, &Bs[0][boff]);
    g2lds16(BgB1, &Bs[0][boff + 512]);

    f32x4 acc[2][4] = {};
    int buf = 0;
    for (int k0 = 0; k0 < K; k0 += 32) {
        __syncthreads();
        if (k0 + 32 < K) {
            g2lds16(AgB + k0 + 32, &As[buf ^ 1][aoff]);
            g2lds16(BgB0 + k0 + 32, &Bs[buf ^ 1][boff]);
            g2lds16(BgB1 + k0 + 32, &Bs[buf ^ 1][boff + 512]);
        }
        bf16x8 af[2], bfr[4];
        #pragma unroll
        for (int mi = 0; mi < 2; ++mi)
            af[mi] = *(const bf16x8*)&As[buf][(wm * 32 + mi * 16 + ln) * 32 + pc * 8];
        #pragma unroll
        for (int ni = 0; ni < 4; ++ni)
            bfr[ni] = *(const bf16x8*)&Bs[buf][(wn * 64 + ni * 16 + ln) * 32 + pc * 8];
        #pragma unroll
        for (int mi = 0; mi < 2; ++mi)
            #pragma unroll
            for (int ni = 0; ni < 4; ++ni)
                acc[mi][ni] = __builtin_amdgcn_mfma_f32_16x16x32_bf16(
                    af[mi], bfr[ni], acc[mi][ni], 0, 0, 0);
        buf ^= 1;
    }

    const int head = blockIdx.y * 2 + wn;
    const int b = m0 >> 11;
    const size_t bh = (size_t)b * H_ + head;
    if (z == 0) {
        #pragma unroll
        for (int mi = 0; mi < 2; ++mi) {
            const int s = (m0 & (S_ - 1)) + wm * 32 + mi * 16 + quad * 4;
            #pragma unroll
            for (int ni = 0; ni < 4; ++ni) {
                const int d = ni * 16 + ln;
                ushort4 o;
                o.x = f2bf(acc[mi][ni][0]); o.y = f2bf(acc[mi][ni][1]);
                o.z = f2bf(acc[mi][ni][2]); o.w = f2bf(acc[mi][ni][3]);
                *(ushort4*)(co + (bh * 64 + d) * S_ + s) = o;
            }
        }
        float a4[4];
        #pragma unroll
        for (int ni = 0; ni < 4; ++ni) a4[ni] = ar[ni * 16 + ln];
        #pragma unroll
        for (int mi = 0; mi < 2; ++mi) {
            const int s = (m0 & (S_ - 1)) + wm * 32 + mi * 16 + quad * 4;
            #pragma unroll
            for (int r = 0; r < 4; ++r) {
                float v = 0.f;
                #pragma unroll
                for (int ni = 0; ni < 4; ++ni)
                    v += leaky(acc[mi][ni][r]) * a4[ni];
                #pragma unroll
                for (int off = 8; off; off >>= 1) v += __shfl_xor(v, off, 16);
                if (ln == 0) sred[bh * S_ + s + r] = v * scl;
            }
        }
    } else {
        #pragma unroll
        for (int mi = 0; mi < 2; ++mi) {
            const int s = (m0 & (S_ - 1)) + wm * 32 + mi * 16 + quad * 4;
            #pragma unroll
            for (int ni = 0; ni < 4; ++ni) {
                const int d = ni * 16 + ln;
                #pragma unroll
                for (int r = 0; r < 4; ++r)
                    co[(bh * S_ + s + r) * 64 + d] = f2bf(acc[mi][ni][r] * scl);
            }
        }
    }
}

// ---------------------------------------------------------------------------
// Flash attention, bf16 MFMA. 128 q/block, 4-buffer depth-2 counted-vmcnt
// pipeline + T15 lag-1 double-pipeline (round 3 structure). ROUND 4 FIX:
// __launch_bounds__(256, 1) — the (256,2) cap at 128 VGPRs forced ~60
// in-loop spills (WRITE_SIZE 14.8 -> 108.8 MB, MfmaUtil 24 -> 15.5%).
// Demand is ~190-210 VGPRs, still <= 256/wave => HW occupancy remains
// 2 waves/SIMD (2 blocks/CU via 80 KB LDS), now spill-free.
// ---------------------------------------------------------------------------
#define WAITV(N) asm volatile("s_waitcnt vmcnt(" #N ")" ::: "memory")
#define BARR()   __builtin_amdgcn_s_barrier()

__global__ __launch_bounds__(256, 1) void attn_mfma(
    const ushort* __restrict__ frT, const ushort* __restrict__ rk,
    const ushort* __restrict__ rq, const float* __restrict__ sr,
    ushort* __restrict__ hsa)
{
    __shared__ ushort RQ[4][64][64];   // 32 KB
    __shared__ ushort FT[4][64][64];   // 32 KB
    __shared__ ushort PS[8][16][64];   // 16 KB (per-wave strips, no x-wave sharing)

    const int tid = threadIdx.x;
    const int w = tid >> 6;
    const int lane = tid & 63;
    const int ln = lane & 15;
    const int quad = lane >> 4;

    // bijective XCD swizzle over 512 blocks: 64/XCD = 4 full (b,h) groups
    const int flat = blockIdx.x + 16 * (blockIdx.y + 8 * blockIdx.z); // 0..511
    const int wid = (flat & 7) * 64 + (flat >> 3);
    const int q0 = (wid & 15) * 128;
    const int h = (wid >> 4) & 7;
    const int b = wid >> 7;
    const size_t bh = (size_t)b * H_ + h;

    // A-frags (rk): q = q0 + 32w + 16qs + ln
    bf16x8 a[2][2];
    #pragma unroll
    for (int qs = 0; qs < 2; ++qs) {
        const ushort* p = rk + ((bh * S_ + q0 + 32 * w + 16 * qs + ln) << 6);
        a[qs][0] = *(const bf16x8*)(p + quad * 8);
        a[qs][1] = *(const bf16x8*)(p + 32 + quad * 8);
    }

    const ushort* rq_g = rq + (bh * S_ << 6);
    const ushort* ft_g = frT + (size_t)bh * 64 * S_;
    const float* srp = sr + bh * S_;

    // staging: block covers tile rows 0..63 (wave w: [16w,16w+16), 2x8 rows)
    const int rl = lane >> 3;
    const int pg = lane & 7;
    const int row_b = w * 16 + rl;
    const int sgF = (pg - rl) & 7;                    // FT swizzle (g+row)&7
    const int sgR0 = (pg - 4 * w - (rl >> 2)) & 7;    // RQ swizzle (g+(row>>2))&7
    const int sgR1 = (pg - 4 * w - 2 - (rl >> 2)) & 7;

    #define STAGE(BUF, t0)                                                    \
        {                                                                     \
            g2lds16(rq_g + ((size_t)((t0) + row_b) << 6) + sgR0 * 8,          \
                    &RQ[BUF][row_b][pg * 8]);                                 \
            g2lds16(rq_g + ((size_t)((t0) + row_b + 8) << 6) + sgR1 * 8,      \
                    &RQ[BUF][row_b + 8][pg * 8]);                             \
            g2lds16(ft_g + (size_t)row_b * S_ + (t0) + sgF * 8,               \
                    &FT[BUF][row_b][pg * 8]);                                 \
            g2lds16(ft_g + (size_t)(row_b + 8) * S_ + (t0) + sgF * 8,         \
                    &FT[BUF][row_b + 8][pg * 8]);                             \
        }

    // hoisted LDS read bases (+ BI*4096 selects buffer)
    const ushort* rqrA = &RQ[0][0][0] + 4 * ln * 64 + ((quad + ln) & 7) * 8;
    const ushort* rqrB = &RQ[0][0][0] + 4 * ln * 64 + ((quad + 4 + ln) & 7) * 8;
    const ushort* ftrA = &FT[0][0][0] + ln * 64 + ((quad + ln) & 7) * 8;
    const ushort* ftrB = &FT[0][0][0] + ln * 64 + ((quad + 4 + ln) & 7) * 8;
    // PS strip pointers (per qs)
    ushort* sb[2];
    sb[0] = &PS[w * 2][0][0]; sb[1] = &PS[w * 2 + 1][0][0];
    int wr_off[4];
    #pragma unroll
    for (int r = 0; r < 4; ++r) {
        const int prow = quad * 4 + r;
        wr_off[r] = prow * 64 + (((ln >> 1) + prow) & 7) * 8 + (ln & 1) * 4;
    }
    const int rd0 = ln * 64 + ((quad + ln) & 7) * 8;
    const int rd1 = ln * 64 + ((quad + 4 + ln) & 7) * 8;

    float lsum[2][4] = {};
    f32x4 ctx[2][4] = {};
    f32x4 scA[2][4], scB[2][4];

    // QK^T(half in buffer BI) -> SC; results consumed one slot later
    #define QKT(BI, SC)                                                       \
        {                                                                     \
            __builtin_amdgcn_s_setprio(1);                                    \
            _Pragma("unroll")                                                 \
            for (int jb = 0; jb < 4; ++jb) {                                  \
                const bf16x8 b0 = *(const bf16x8*)(rqrA + (BI) * 4096 + jb * 64); \
                const bf16x8 b1 = *(const bf16x8*)(rqrB + (BI) * 4096 + jb * 64); \
                _Pragma("unroll")                                             \
                for (int qs = 0; qs < 2; ++qs) {                              \
                    f32x4 tt = {0.f, 0.f, 0.f, 0.f};                          \
                    tt = __builtin_amdgcn_mfma_f32_16x16x32_bf16(a[qs][0], b0, tt, 0, 0, 0); \
                    tt = __builtin_amdgcn_mfma_f32_16x16x32_bf16(a[qs][1], b1, tt, 0, 0, 0); \
                    SC[qs][jb] = tt;                                          \
                }                                                             \
            }                                                                 \
            __builtin_amdgcn_s_setprio(0);                                    \
        }

    // softmax + PV for the PREVIOUS half: scores SC, bias SV, FT buffer BJ
    #define SMPV(SC, SV, BJ)                                                  \
        {                                                                     \
            _Pragma("unroll")                                                 \
            for (int qs = 0; qs < 2; ++qs)                                    \
                _Pragma("unroll")                                             \
                for (int r = 0; r < 4; ++r) {                                 \
                    const float p0 = __builtin_amdgcn_exp2f(SC[qs][0][r] + SV.x); \
                    const float p1 = __builtin_amdgcn_exp2f(SC[qs][1][r] + SV.y); \
                    const float p2 = __builtin_amdgcn_exp2f(SC[qs][2][r] + SV.z); \
                    const float p3 = __builtin_amdgcn_exp2f(SC[qs][3][r] + SV.w); \
                    lsum[qs][r] += (p0 + p1) + (p2 + p3);                      \
                    const unsigned lo = (fbits(p0) >> 16) | (fbits(p1) & 0xffff0000u); \
                    const unsigned hi = (fbits(p2) >> 16) | (fbits(p3) & 0xffff0000u); \
                    *(uint2*)(sb[qs] + wr_off[r]) = make_uint2(lo, hi);       \
                }                                                             \
            const bf16x8 pa00 = *(const bf16x8*)(sb[0] + rd0);                \
            const bf16x8 pa01 = *(const bf16x8*)(sb[0] + rd1);                \
            const bf16x8 pa10 = *(const bf16x8*)(sb[1] + rd0);                \
            const bf16x8 pa11 = *(const bf16x8*)(sb[1] + rd1);                \
            __builtin_amdgcn_s_setprio(1);                                    \
            _Pragma("unroll")                                                 \
            for (int jb = 0; jb < 4; ++jb) {                                  \
                const bf16x8 fb0 = *(const bf16x8*)(ftrA + (BJ) * 4096 + jb * 1024); \
                const bf16x8 fb1 = *(const bf16x8*)(ftrB + (BJ) * 4096 + jb * 1024); \
                ctx[0][jb] = __builtin_amdgcn_mfma_f32_16x16x32_bf16(pa00, fb0, ctx[0][jb], 0, 0, 0); \
                ctx[0][jb] = __builtin_amdgcn_mfma_f32_16x16x32_bf16(pa01, fb1, ctx[0][jb], 0, 0, 0); \
                ctx[1][jb] = __builtin_amdgcn_mfma_f32_16x16x32_bf16(pa10, fb0, ctx[1][jb], 0, 0, 0); \
                ctx[1][jb] = __builtin_amdgcn_mfma_f32_16x16x32_bf16(pa11, fb1, ctx[1][jb], 0, 0, 0); \
            }                                                                 \
            __builtin_amdgcn_s_setprio(0);                                    \
        }

    float4 sv0, sv1, sv2, sv3;
    // prologue: issue groups for halves 0,1
    STAGE(0, 0)   sv0 = *(const float4*)(srp + 0 + 4 * ln);
    STAGE(1, 64)  sv1 = *(const float4*)(srp + 64 + 4 * ln);

    // slot 0: QKT(0) only (nothing to finish yet)
    WAITV(5); BARR();
    STAGE(2, 128) sv2 = *(const float4*)(srp + 128 + 4 * ln);
    QKT(0, scA)
    // slot 1
    WAITV(5); BARR();
    STAGE(3, 192) sv3 = *(const float4*)(srp + 192 + 4 * ln);
    QKT(1, scB)
    SMPV(scA, sv0, 0)

    // steady state: slots 2..29 (7 x 4)
    for (int k = 0; k < 7; ++k) {
        const int t0 = k * 256;
        WAITV(5); BARR();
        STAGE(0, t0 + 256) sv0 = *(const float4*)(srp + t0 + 256 + 4 * ln);
        QKT(2, scA)
        SMPV(scB, sv1, 1)
        WAITV(5); BARR();
        STAGE(1, t0 + 320) sv1 = *(const float4*)(srp + t0 + 320 + 4 * ln);
        QKT(3, scB)
        SMPV(scA, sv2, 2)
        WAITV(5); BARR();
        STAGE(2, t0 + 384) sv2 = *(const float4*)(srp + t0 + 384 + 4 * ln);
        QKT(0, scA)
        SMPV(scB, sv3, 3)
        WAITV(5); BARR();
        STAGE(3, t0 + 448) sv3 = *(const float4*)(srp + t0 + 448 + 4 * ln);
        QKT(1, scB)
        SMPV(scA, sv0, 0)
    }
    // tail: slots 30,31 + flush (halves 30,31 staged at slots 28,29)
    WAITV(5); BARR();
    QKT(2, scA)            // half 30
    SMPV(scB, sv1, 1)      // half 29
    WAITV(0); BARR();
    QKT(3, scB)            // half 31
    SMPV(scA, sv2, 2)      // half 30
    SMPV(scB, sv3, 3)      // half 31 (flush)

    #pragma unroll
    for (int qs = 0; qs < 2; ++qs)
        #pragma unroll
        for (int r = 0; r < 4; ++r) {
            float l = lsum[qs][r];
            #pragma unroll
            for (int off = 8; off; off >>= 1) l += __shfl_xor(l, off, 16);
            const float inv = 1.f / l;
            const int q = q0 + 32 * w + 16 * qs + quad * 4 + r;
            ushort* orow = hsa + (size_t)(b * S_ + q) * D_ + h * 64;
            #pragma unroll
            for (int jb = 0; jb < 4; ++jb)
                orow[16 * jb + ln] = f2bf(ctx[qs][jb][r] * inv);
        }
}

// ---------------------------------------------------------------------------
// final projection GEMM (fp32 out), double-buffered
// ---------------------------------------------------------------------------
__global__ __launch_bounds__(256) void gemm_out(
    const ushort* __restrict__ A, const ushort* __restrict__ WT,
    float* __restrict__ C)
{
    __shared__ ushort As[2][64 * 32];
    __shared__ ushort Bs[2][128 * 32];

    const int tid = threadIdx.x;
    const int lane = tid & 63, w = tid >> 6;
    const int ln = lane & 15, quad = lane >> 4;
    const int wm = w >> 1, wn = w & 1;
    const int m0 = blockIdx.x * 64, n0 = blockIdx.y * 128;
    const int K = 512;

    const int srA = tid >> 2;
    const int lchA = ((lane & 3) - (srA >> 1)) & 3;
    const ushort* AgB = A + (size_t)(m0 + srA) * K + lchA * 8;
    const int srB = w * 32 + (lane >> 2);
    const int lchB = ((lane & 3) - (srB >> 1)) & 3;
    const ushort* BgB0 = WT + (size_t)(n0 + srB) * K + lchB * 8;
    const ushort* BgB1 = BgB0 + (size_t)16 * K;
    const int aoff = tid * 8;
    const int boff = srB * 32 + (lane & 3) * 8;
    const int pc = (quad + (ln >> 1)) & 3;

    g2lds16(AgB, &As[0][aoff]);
    g2lds16(BgB0, &Bs[0][boff]);
    g2lds16(BgB1, &Bs[0][boff + 512]);

    f32x4 acc[2][4] = {};
    int buf = 0;
    for (int k0 = 0; k0 < K; k0 += 32) {
        __syncthreads();
        if (k0 + 32 < K) {
            g2lds16(AgB + k0 + 32, &As[buf ^ 1][aoff]);
            g2lds16(BgB0 + k0 + 32, &Bs[buf ^ 1][boff]);
            g2lds16(BgB1 + k0 + 32, &Bs[buf ^ 1][boff + 512]);
        }
        bf16x8 af[2], bfr[4];
        #pragma unroll
        for (int mi = 0; mi < 2; ++mi)
            af[mi] = *(const bf16x8*)&As[buf][(wm * 32 + mi * 16 + ln) * 32 + pc * 8];
        #pragma unroll
        for (int ni = 0; ni < 4; ++ni)
            bfr[ni] = *(const bf16x8*)&Bs[buf][(wn * 64 + ni * 16 + ln) * 32 + pc * 8];
        #pragma unroll
        for (int mi = 0; mi < 2; ++mi)
            #pragma unroll
            for (int ni = 0; ni < 4; ++ni)
                acc[mi][ni] = __builtin_amdgcn_mfma_f32_16x16x32_bf16(
                    af[mi], bfr[ni], acc[mi][ni], 0, 0, 0);
        buf ^= 1;
    }

    #pragma unroll
    for (int mi = 0; mi < 2; ++mi) {
        const int row = m0 + wm * 32 + mi * 16 + quad * 4;
        #pragma unroll
        for (int ni = 0; ni < 4; ++ni) {
            const int col = n0 + wn * 64 + ni * 16 + ln;
            #pragma unroll
            for (int r = 0; r < 4; ++r)
                C[(size_t)(row + r) * 512 + col] = acc[mi][ni][r];
        }
    }
}

// ---------------------------------------------------------------------------
// LayerNorm(h + fh) * g + b
// ---------------------------------------------------------------------------
__global__ __launch_bounds__(256) void ln_kernel(
    const float* __restrict__ h, const float* __restrict__ fh,
    const float* __restrict__ g, const float* __restrict__ bb,
    float* __restrict__ out)
{
    const int row = blockIdx.x, tid = threadIdx.x;
    const float* hp = h + (size_t)row * 512;
    const float* fp = fh + (size_t)row * 512;
    const float x0 = hp[tid] + fp[tid];
    const float x1 = hp[tid + 256] + fp[tid + 256];
    __shared__ float red[4];

    float s = x0 + x1;
    #pragma unroll
    for (int off = 32; off; off >>= 1) s += __shfl_xor(s, off, 64);
    if ((tid & 63) == 0) red[tid >> 6] = s;
    __syncthreads();
    const float mu = (red[0] + red[1] + red[2] + red[3]) * (1.f / 512.f);

    const float d0 = x0 - mu, d1 = x1 - mu;
    float v = d0 * d0 + d1 * d1;
    #pragma unroll
    for (int off = 32; off; off >>= 1) v += __shfl_xor(v, off, 64);
    __syncthreads();
    if ((tid & 63) == 0) red[tid >> 6] = v;
    __syncthreads();
    const float var = (red[0] + red[1] + red[2] + red[3]) * (1.f / 512.f);
    const float inv = rsqrtf(var + LN_EPS);

    out[(size_t)row * 512 + tid] = d0 * inv * g[tid] + bb[tid];
    out[(size_t)row * 512 + tid + 256] = d1 * inv * g[tid + 256] + bb[tid + 256];
}

// ---------------------------------------------------------------------------
extern "C" void kernel_launch(void* const* d_in, const int* in_sizes, int n_in,
                              void* d_out, int out_size, void* d_ws, size_t ws_size,
                              hipStream_t stream)
{
    const float* h   = (const float*)d_in[0];
    const float* rh  = (const float*)d_in[1];
    // d_in[2] = Wl, d_in[4] = al : unused — sl cancels in softmax
    const float* Wr  = (const float*)d_in[3];
    const float* ar  = (const float*)d_in[5];
    const float* Wrs = (const float*)d_in[6];
    const float* Wrt = (const float*)d_in[7];
    const float* Wf  = (const float*)d_in[8];
    const float* lng = (const float*)d_in[9];
    const float* lnb = (const float*)d_in[10];
    float* out = (float*)d_out;
    char* wsb  = (char*)d_ws;

    const size_t MB = (size_t)1 << 20;
    ushort* hb   = (ushort*)(wsb);               //  8 MB
    ushort* rhb  = (ushort*)(wsb + 8 * MB);      //  1 MB
    ushort* WrT  = (ushort*)(wsb + 9 * MB);      // .5 MB
    ushort* WfT  = (ushort*)(wsb + 9 * MB + 512 * 1024);
    ushort* WrsT = (ushort*)(wsb + 10 * MB);     // 64 KB
    ushort* WrtT = (ushort*)(wsb + 10 * MB + 64 * 1024);
    ushort* frT  = (ushort*)(wsb + 11 * MB);     //  8 MB  [B,H,64,S]
    ushort* rkw  = (ushort*)(wsb + 19 * MB);     //  8 MB  [B,H,S,64]
    ushort* rqw  = (ushort*)(wsb + 27 * MB);     //  8 MB  [B,H,S,64]
    float*  sr   = (float*) (wsb + 35 * MB);     // .25MB  [B,H,S]
    ushort* hsab = (ushort*)(wsb + 36 * MB);     //  8 MB  [B,S,512] bf16
    float*  fh   = (float*) (wsb + 44 * MB);     // 16 MB  [B,S,512] f32

    dim3 blk(256);
    prep<<<dim3(4752), blk, 0, stream>>>(h, rh, Wr, Wf, Wrs, Wrt,
                                         hb, rhb, WrT, WfT, WrsT, WrtT);
    proj<<<dim3(128, 4, 3), blk, 0, stream>>>(hb, rhb, WrT, WrsT, WrtT,
                                              frT, rkw, rqw, sr, ar);
    // attention: 128 q/block, depth-2 counted-vmcnt + lag-1 double-pipeline
    attn_mfma<<<dim3(S_ / 128, H_, B_), blk, 0, stream>>>(frT, rkw, rqw, sr, hsab);
    gemm_out<<<dim3(128, 4), blk, 0, stream>>>(hsab, WfT, fh);
    ln_kernel<<<dim3(B_ * S_), blk, 0, stream>>>(h, fh, lng, lnb, out);
}

// Round 5
// 176.750 us; speedup vs baseline: 1.1645x; 1.0670x over previous
//
#include <hip/hip_runtime.h>
#include <math.h>

#define B_ 4
#define S_ 2048
#define D_ 512
#define H_ 8
#define HD_ 64
#define RL_ 64
#define LN_EPS 1e-5f
#define SLOPE 0.01f
#define LOG2E 1.4426950408889634f

typedef __attribute__((ext_vector_type(8))) __bf16 bf16x8;
typedef __attribute__((ext_vector_type(4))) float f32x4;

__device__ __forceinline__ float leaky(float x) { return x >= 0.f ? x : SLOPE * x; }

// float -> bf16 (RNE)
__device__ __forceinline__ ushort f2bf(float f) {
    union { float f; unsigned u; } v; v.f = f;
    unsigned r = v.u + 0x7fffu + ((v.u >> 16) & 1u);
    return (ushort)(r >> 16);
}
__device__ __forceinline__ unsigned fbits(float f) {
    union { float f; unsigned u; } v; v.f = f; return v.u;
}

__device__ __forceinline__ void g2lds16(const void* g, void* l) {
    __builtin_amdgcn_global_load_lds(
        (const __attribute__((address_space(1))) void*)(uintptr_t)g,
        (__attribute__((address_space(3))) void*)(uintptr_t)l, 16, 0, 0);
}

// ---------------------------------------------------------------------------
// prep (merged): grid 4752
// ---------------------------------------------------------------------------
__global__ __launch_bounds__(256) void prep(
    const float* __restrict__ h, const float* __restrict__ rh,
    const float* __restrict__ Wr, const float* __restrict__ Wf,
    const float* __restrict__ Wrs, const float* __restrict__ Wrt,
    ushort* __restrict__ hb, ushort* __restrict__ rhb,
    ushort* __restrict__ WrT, ushort* __restrict__ WfT,
    ushort* __restrict__ WrsT, ushort* __restrict__ WrtT)
{
    const int bx = blockIdx.x, tid = threadIdx.x;
    if (bx < 4608) {
        const float* in = (bx < 4096) ? h : rh;
        ushort* o = (bx < 4096) ? hb : rhb;
        const int i = (bx < 4096 ? bx : bx - 4096) * 256 + tid;
        const float4 v = ((const float4*)in)[i];
        ushort4 u; u.x = f2bf(v.x); u.y = f2bf(v.y); u.z = f2bf(v.z); u.w = f2bf(v.w);
        ((ushort4*)o)[i] = u;
        return;
    }
    __shared__ float TS[64][65];
    int t = bx - 4608;
    const float* in; ushort* out; int K, tk, tn;
    if (t < 64)       { in = Wr;  out = WrT;  K = 512; tk = t & 7; tn = t >> 3; }
    else if (t < 128) { in = Wf;  out = WfT;  K = 512; t -= 64; tk = t & 7; tn = t >> 3; }
    else if (t < 136) { in = Wrs; out = WrsT; K = 64;  tk = 0; tn = t - 128; }
    else              { in = Wrt; out = WrtT; K = 64;  tk = 0; tn = t - 136; }
    const int k0 = tk * 64, n0 = tn * 64;
    const int r = tid >> 4, c4 = (tid & 15) * 4;
    #pragma unroll
    for (int p = 0; p < 4; ++p) {
        const int row = r + 16 * p;
        const float4 v = *(const float4*)(in + (size_t)(k0 + row) * 512 + n0 + c4);
        TS[row][c4] = v.x; TS[row][c4 + 1] = v.y;
        TS[row][c4 + 2] = v.z; TS[row][c4 + 3] = v.w;
    }
    __syncthreads();
    #pragma unroll
    for (int p = 0; p < 4; ++p) {
        const int nn = r + 16 * p;
        ushort4 o;
        o.x = f2bf(TS[c4 + 0][nn]); o.y = f2bf(TS[c4 + 1][nn]);
        o.z = f2bf(TS[c4 + 2][nn]); o.w = f2bf(TS[c4 + 3][nn]);
        *(ushort4*)(out + (size_t)(n0 + nn) * K + k0 + c4) = o;
    }
}

// ---------------------------------------------------------------------------
// proj (fused): grid (128,4,3). z=0: fr-projection (K=512) -> frT bf16 + sr;
// z=1: rk (K=64, xLOG2E); z=2: rq (K=64).
// ---------------------------------------------------------------------------
__global__ __launch_bounds__(256) void proj(
    const ushort* __restrict__ hb, const ushort* __restrict__ rhb,
    const ushort* __restrict__ WrT, const ushort* __restrict__ WrsT,
    const ushort* __restrict__ WrtT,
    ushort* __restrict__ frT, ushort* __restrict__ rkw, ushort* __restrict__ rqw,
    float* __restrict__ sred, const float* __restrict__ ar)
{
    __shared__ ushort As[2][64 * 32];
    __shared__ ushort Bs[2][128 * 32];

    const int tid = threadIdx.x;
    const int lane = tid & 63, w = tid >> 6;
    const int ln = lane & 15, quad = lane >> 4;
    const int wm = w >> 1, wn = w & 1;
    const int m0 = blockIdx.x * 64, n0 = blockIdx.y * 128;
    const int z = blockIdx.z;

    const ushort* A; const ushort* wt; ushort* co; float scl; int K;
    if (z == 0)      { A = hb;  wt = WrT;  co = frT; scl = LOG2E; K = 512; }
    else if (z == 1) { A = rhb; wt = WrsT; co = rkw; scl = LOG2E; K = 64; }
    else             { A = rhb; wt = WrtT; co = rqw; scl = 1.0f;  K = 64; }

    const int srA = tid >> 2;
    const int lchA = ((lane & 3) - (srA >> 1)) & 3;
    const ushort* AgB = A + (size_t)(m0 + srA) * K + lchA * 8;
    const int srB = w * 32 + (lane >> 2);
    const int lchB = ((lane & 3) - (srB >> 1)) & 3;
    const ushort* BgB0 = wt + (size_t)(n0 + srB) * K + lchB * 8;
    const ushort* BgB1 = BgB0 + (size_t)16 * K;
    const int aoff = tid * 8;
    const int boff = srB * 32 + (lane & 3) * 8;
    const int pc = (quad + (ln >> 1)) & 3;

    g2lds16(AgB, &As[0][aoff]);
    g2lds16(BgB0, &Bs[0][boff]);
    g2lds16(BgB1, &Bs[0][boff + 512]);

    f32x4 acc[2][4] = {};
    int buf = 0;
    for (int k0 = 0; k0 < K; k0 += 32) {
        __syncthreads();
        if (k0 + 32 < K) {
            g2lds16(AgB + k0 + 32, &As[buf ^ 1][aoff]);
            g2lds16(BgB0 + k0 + 32, &Bs[buf ^ 1][boff]);
            g2lds16(BgB1 + k0 + 32, &Bs[buf ^ 1][boff + 512]);
        }
        bf16x8 af[2], bfr[4];
        #pragma unroll
        for (int mi = 0; mi < 2; ++mi)
            af[mi] = *(const bf16x8*)&As[buf][(wm * 32 + mi * 16 + ln) * 32 + pc * 8];
        #pragma unroll
        for (int ni = 0; ni < 4; ++ni)
            bfr[ni] = *(const bf16x8*)&Bs[buf][(wn * 64 + ni * 16 + ln) * 32 + pc * 8];
        #pragma unroll
        for (int mi = 0; mi < 2; ++mi)
            #pragma unroll
            for (int ni = 0; ni < 4; ++ni)
                acc[mi][ni] = __builtin_amdgcn_mfma_f32_16x16x32_bf16(
                    af[mi], bfr[ni], acc[mi][ni], 0, 0, 0);
        buf ^= 1;
    }

    const int head = blockIdx.y * 2 + wn;
    const int b = m0 >> 11;
    const size_t bh = (size_t)b * H_ + head;
    if (z == 0) {
        #pragma unroll
        for (int mi = 0; mi < 2; ++mi) {
            const int s = (m0 & (S_ - 1)) + wm * 32 + mi * 16 + quad * 4;
            #pragma unroll
            for (int ni = 0; ni < 4; ++ni) {
                const int d = ni * 16 + ln;
                ushort4 o;
                o.x = f2bf(acc[mi][ni][0]); o.y = f2bf(acc[mi][ni][1]);
                o.z = f2bf(acc[mi][ni][2]); o.w = f2bf(acc[mi][ni][3]);
                *(ushort4*)(co + (bh * 64 + d) * S_ + s) = o;
            }
        }
        float a4[4];
        #pragma unroll
        for (int ni = 0; ni < 4; ++ni) a4[ni] = ar[ni * 16 + ln];
        #pragma unroll
        for (int mi = 0; mi < 2; ++mi) {
            const int s = (m0 & (S_ - 1)) + wm * 32 + mi * 16 + quad * 4;
            #pragma unroll
            for (int r = 0; r < 4; ++r) {
                float v = 0.f;
                #pragma unroll
                for (int ni = 0; ni < 4; ++ni)
                    v += leaky(acc[mi][ni][r]) * a4[ni];
                #pragma unroll
                for (int off = 8; off; off >>= 1) v += __shfl_xor(v, off, 16);
                if (ln == 0) sred[bh * S_ + s + r] = v * scl;
            }
        }
    } else {
        #pragma unroll
        for (int mi = 0; mi < 2; ++mi) {
            const int s = (m0 & (S_ - 1)) + wm * 32 + mi * 16 + quad * 4;
            #pragma unroll
            for (int ni = 0; ni < 4; ++ni) {
                const int d = ni * 16 + ln;
                #pragma unroll
                for (int r = 0; r < 4; ++r)
                    co[(bh * S_ + s + r) * 64 + d] = f2bf(acc[mi][ni][r] * scl);
            }
        }
    }
}

// ---------------------------------------------------------------------------
// Flash attention, bf16 MFMA. Round 5: R2's proven dataflow (Q_w=32, no lag,
// no setprio) split into SMALL SYNC DOMAINS: 128-thread blocks (2 waves,
// 64 q), grid 1024, LDS 40 KB -> exactly 4 blocks/CU. Per-wave LDS/VALU/MFMA
// work per output is unchanged vs R2; 4 independent barrier domains per CU
// de-phase so LDS, VALU and MFMA pipes run concurrently instead of taking
// turns (R1-R4 showed the plateau = serial-sum of pipe times).
// Depth-1 prefetch, wait BEFORE barrier (R2-proven publish order):
//   slot s: WAITV(0) [G(s) landed, issued a full slot ago]; BARR;
//           STAGE(s+1) [other buffer]; COMPUTE(s).
// ---------------------------------------------------------------------------
#define WAITV(N) asm volatile("s_waitcnt vmcnt(" #N ")" ::: "memory")
#define BARR()   __builtin_amdgcn_s_barrier()

__global__ __launch_bounds__(128, 2) void attn_mfma(
    const ushort* __restrict__ frT, const ushort* __restrict__ rk,
    const ushort* __restrict__ rq, const float* __restrict__ sr,
    ushort* __restrict__ hsa)
{
    __shared__ ushort RQ[2][64][64];   // 16 KB
    __shared__ ushort FT[2][64][64];   // 16 KB
    __shared__ ushort PS[4][16][64];   //  8 KB (per-(wave,qs) strips)

    const int tid = threadIdx.x;
    const int w = tid >> 6;            // 0..1
    const int lane = tid & 63;
    const int ln = lane & 15;
    const int quad = lane >> 4;

    // bijective XCD swizzle over 1024 blocks: 128/XCD = 4 full (b,h) groups
    const int flat = blockIdx.x + 32 * (blockIdx.y + 8 * blockIdx.z); // 0..1023
    const int wid = (flat & 7) * 128 + (flat >> 3);
    const int q0 = (wid & 31) * 64;
    const int h = (wid >> 5) & 7;
    const int b = wid >> 8;
    const size_t bh = (size_t)b * H_ + h;

    // A-frags (rk): q = q0 + 32w + 16qs + ln
    bf16x8 a[2][2];
    #pragma unroll
    for (int qs = 0; qs < 2; ++qs) {
        const ushort* p = rk + ((bh * S_ + q0 + 32 * w + 16 * qs + ln) << 6);
        a[qs][0] = *(const bf16x8*)(p + quad * 8);
        a[qs][1] = *(const bf16x8*)(p + 32 + quad * 8);
    }

    const ushort* rq_g = rq + (bh * S_ << 6);
    const ushort* ft_g = frT + (size_t)bh * 64 * S_;
    const float* srp = sr + bh * S_;

    // staging with 128 threads: each thread covers 4 rows per array.
    // wave w: rows 32w + rl + 8m (m=0..3). LDS dest is lane-linear per issue
    // (base + lane*16), as global_load_lds requires.
    // RQ granule shift = (row>>2)&7 ; FT granule shift = row&7  (both proven).
    const int rl = lane >> 3;          // 0..7
    const int pg = lane & 7;           // granule
    const int base_row = w * 32 + rl;
    const int sgF = (pg - rl) & 7;

    #define STAGE(BUF, t0)                                                    \
        {                                                                     \
            _Pragma("unroll")                                                 \
            for (int m = 0; m < 4; ++m) {                                     \
                const int rr = base_row + 8 * m;                              \
                const int sgR = (pg - ((rr >> 2) & 7)) & 7;                   \
                g2lds16(rq_g + ((size_t)((t0) + rr) << 6) + sgR * 8,          \
                        &RQ[BUF][rr][pg * 8]);                                \
                g2lds16(ft_g + (size_t)rr * S_ + (t0) + sgF * 8,              \
                        &FT[BUF][rr][pg * 8]);                                \
            }                                                                 \
        }

    // hoisted LDS read bases (+ BI*4096 ushorts selects buffer)
    const ushort* rqrA = &RQ[0][0][0] + 4 * ln * 64 + ((quad + ln) & 7) * 8;
    const ushort* rqrB = &RQ[0][0][0] + 4 * ln * 64 + ((quad + 4 + ln) & 7) * 8;
    const ushort* ftrA = &FT[0][0][0] + ln * 64 + ((quad + ln) & 7) * 8;
    const ushort* ftrB = &FT[0][0][0] + ln * 64 + ((quad + 4 + ln) & 7) * 8;
    // PS strip pointers (per qs)
    ushort* sb[2];
    sb[0] = &PS[w * 2][0][0]; sb[1] = &PS[w * 2 + 1][0][0];
    int wr_off[4];
    #pragma unroll
    for (int r = 0; r < 4; ++r) {
        const int prow = quad * 4 + r;
        wr_off[r] = prow * 64 + (((ln >> 1) + prow) & 7) * 8 + (ln & 1) * 4;
    }
    const int rd0 = ln * 64 + ((quad + ln) & 7) * 8;
    const int rd1 = ln * 64 + ((quad + 4 + ln) & 7) * 8;

    float lsum[2][4] = {};
    f32x4 ctx[2][4] = {};

    #define COMPUTE(BI, SV)                                                        \
        {                                                                          \
            f32x4 sc[2][4];                                                        \
            _Pragma("unroll")                                                      \
            for (int jb = 0; jb < 4; ++jb) {                                       \
                const bf16x8 b0 = *(const bf16x8*)(rqrA + (BI) * 4096 + jb * 64);  \
                const bf16x8 b1 = *(const bf16x8*)(rqrB + (BI) * 4096 + jb * 64);  \
                _Pragma("unroll")                                                  \
                for (int qs = 0; qs < 2; ++qs) {                                   \
                    f32x4 tt = {0.f, 0.f, 0.f, 0.f};                               \
                    tt = __builtin_amdgcn_mfma_f32_16x16x32_bf16(a[qs][0], b0, tt, 0, 0, 0); \
                    tt = __builtin_amdgcn_mfma_f32_16x16x32_bf16(a[qs][1], b1, tt, 0, 0, 0); \
                    sc[qs][jb] = tt;                                               \
                }                                                                  \
            }                                                                      \
            _Pragma("unroll")                                                      \
            for (int qs = 0; qs < 2; ++qs)                                         \
                _Pragma("unroll")                                                  \
                for (int r = 0; r < 4; ++r) {                                      \
                    const float p0 = __builtin_amdgcn_exp2f(sc[qs][0][r] + SV.x);  \
                    const float p1 = __builtin_amdgcn_exp2f(sc[qs][1][r] + SV.y);  \
                    const float p2 = __builtin_amdgcn_exp2f(sc[qs][2][r] + SV.z);  \
                    const float p3 = __builtin_amdgcn_exp2f(sc[qs][3][r] + SV.w);  \
                    lsum[qs][r] += (p0 + p1) + (p2 + p3);                          \
                    const unsigned lo = (fbits(p0) >> 16) | (fbits(p1) & 0xffff0000u); \
                    const unsigned hi = (fbits(p2) >> 16) | (fbits(p3) & 0xffff0000u); \
                    *(uint2*)(sb[qs] + wr_off[r]) = make_uint2(lo, hi);            \
                }                                                                  \
            const bf16x8 pa00 = *(const bf16x8*)(sb[0] + rd0);                     \
            const bf16x8 pa01 = *(const bf16x8*)(sb[0] + rd1);                     \
            const bf16x8 pa10 = *(const bf16x8*)(sb[1] + rd0);                     \
            const bf16x8 pa11 = *(const bf16x8*)(sb[1] + rd1);                     \
            _Pragma("unroll")                                                      \
            for (int jb = 0; jb < 4; ++jb) {                                       \
                const bf16x8 fb0 = *(const bf16x8*)(ftrA + (BI) * 4096 + jb * 1024); \
                const bf16x8 fb1 = *(const bf16x8*)(ftrB + (BI) * 4096 + jb * 1024); \
                ctx[0][jb] = __builtin_amdgcn_mfma_f32_16x16x32_bf16(pa00, fb0, ctx[0][jb], 0, 0, 0); \
                ctx[0][jb] = __builtin_amdgcn_mfma_f32_16x16x32_bf16(pa01, fb1, ctx[0][jb], 0, 0, 0); \
                ctx[1][jb] = __builtin_amdgcn_mfma_f32_16x16x32_bf16(pa10, fb0, ctx[1][jb], 0, 0, 0); \
                ctx[1][jb] = __builtin_amdgcn_mfma_f32_16x16x32_bf16(pa11, fb1, ctx[1][jb], 0, 0, 0); \
            }                                                                      \
        }

    float4 sv0, sv1;
    // prologue: stage half 0 into buf 0
    STAGE(0, 0)  sv0 = *(const float4*)(srp + 0 + 4 * ln);

    // slots 0..29 (15 x 2). slot s: buf s&1; stages G(s+1) into buf (s+1)&1.
    for (int it = 0; it < 15; ++it) {
        const int t0 = it * 128;
        WAITV(0); BARR();
        STAGE(1, t0 + 64)   sv1 = *(const float4*)(srp + t0 + 64 + 4 * ln);
        COMPUTE(0, sv0)
        WAITV(0); BARR();
        STAGE(0, t0 + 128)  sv0 = *(const float4*)(srp + t0 + 128 + 4 * ln);
        COMPUTE(1, sv1)
    }
    // slot 30: stage G(31)
    WAITV(0); BARR();
    STAGE(1, 1984)  sv1 = *(const float4*)(srp + 1984 + 4 * ln);
    COMPUTE(0, sv0)
    // slot 31
    WAITV(0); BARR();
    COMPUTE(1, sv1)

    #pragma unroll
    for (int qs = 0; qs < 2; ++qs)
        #pragma unroll
        for (int r = 0; r < 4; ++r) {
            float l = lsum[qs][r];
            #pragma unroll
            for (int off = 8; off; off >>= 1) l += __shfl_xor(l, off, 16);
            const float inv = 1.f / l;
            const int q = q0 + 32 * w + 16 * qs + quad * 4 + r;
            ushort* orow = hsa + (size_t)(b * S_ + q) * D_ + h * 64;
            #pragma unroll
            for (int jb = 0; jb < 4; ++jb)
                orow[16 * jb + ln] = f2bf(ctx[qs][jb][r] * inv);
        }
}

// ---------------------------------------------------------------------------
// final projection GEMM (fp32 out), double-buffered
// ---------------------------------------------------------------------------
__global__ __launch_bounds__(256) void gemm_out(
    const ushort* __restrict__ A, const ushort* __restrict__ WT,
    float* __restrict__ C)
{
    __shared__ ushort As[2][64 * 32];
    __shared__ ushort Bs[2][128 * 32];

    const int tid = threadIdx.x;
    const int lane = tid & 63, w = tid >> 6;
    const int ln = lane & 15, quad = lane >> 4;
    const int wm = w >> 1, wn = w & 1;
    const int m0 = blockIdx.x * 64, n0 = blockIdx.y * 128;
    const int K = 512;

    const int srA = tid >> 2;
    const int lchA = ((lane & 3) - (srA >> 1)) & 3;
    const ushort* AgB = A + (size_t)(m0 + srA) * K + lchA * 8;
    const int srB = w * 32 + (lane >> 2);
    const int lchB = ((lane & 3) - (srB >> 1)) & 3;
    const ushort* BgB0 = WT + (size_t)(n0 + srB) * K + lchB * 8;
    const ushort* BgB1 = BgB0 + (size_t)16 * K;
    const int aoff = tid * 8;
    const int boff = srB * 32 + (lane & 3) * 8;
    const int pc = (quad + (ln >> 1)) & 3;

    g2lds16(AgB, &As[0][aoff]);
    g2lds16(BgB0, &Bs[0][boff]);
    g2lds16(BgB1, &Bs[0][boff + 512]);

    f32x4 acc[2][4] = {};
    int buf = 0;
    for (int k0 = 0; k0 < K; k0 += 32) {
        __syncthreads();
        if (k0 + 32 < K) {
            g2lds16(AgB + k0 + 32, &As[buf ^ 1][aoff]);
            g2lds16(BgB0 + k0 + 32, &Bs[buf ^ 1][boff]);
            g2lds16(BgB1 + k0 + 32, &Bs[buf ^ 1][boff + 512]);
        }
        bf16x8 af[2], bfr[4];
        #pragma unroll
        for (int mi = 0; mi < 2; ++mi)
            af[mi] = *(const bf16x8*)&As[buf][(wm * 32 + mi * 16 + ln) * 32 + pc * 8];
        #pragma unroll
        for (int ni = 0; ni < 4; ++ni)
            bfr[ni] = *(const bf16x8*)&Bs[buf][(wn * 64 + ni * 16 + ln) * 32 + pc * 8];
        #pragma unroll
        for (int mi = 0; mi < 2; ++mi)
            #pragma unroll
            for (int ni = 0; ni < 4; ++ni)
                acc[mi][ni] = __builtin_amdgcn_mfma_f32_16x16x32_bf16(
                    af[mi], bfr[ni], acc[mi][ni], 0, 0, 0);
        buf ^= 1;
    }

    #pragma unroll
    for (int mi = 0; mi < 2; ++mi) {
        const int row = m0 + wm * 32 + mi * 16 + quad * 4;
        #pragma unroll
        for (int ni = 0; ni < 4; ++ni) {
            const int col = n0 + wn * 64 + ni * 16 + ln;
            #pragma unroll
            for (int r = 0; r < 4; ++r)
                C[(size_t)(row + r) * 512 + col] = acc[mi][ni][r];
        }
    }
}

// ---------------------------------------------------------------------------
// LayerNorm(h + fh) * g + b
// ---------------------------------------------------------------------------
__global__ __launch_bounds__(256) void ln_kernel(
    const float* __restrict__ h, const float* __restrict__ fh,
    const float* __restrict__ g, const float* __restrict__ bb,
    float* __restrict__ out)
{
    const int row = blockIdx.x, tid = threadIdx.x;
    const float* hp = h + (size_t)row * 512;
    const float* fp = fh + (size_t)row * 512;
    const float x0 = hp[tid] + fp[tid];
    const float x1 = hp[tid + 256] + fp[tid + 256];
    __shared__ float red[4];

    float s = x0 + x1;
    #pragma unroll
    for (int off = 32; off; off >>= 1) s += __shfl_xor(s, off, 64);
    if ((tid & 63) == 0) red[tid >> 6] = s;
    __syncthreads();
    const float mu = (red[0] + red[1] + red[2] + red[3]) * (1.f / 512.f);

    const float d0 = x0 - mu, d1 = x1 - mu;
    float v = d0 * d0 + d1 * d1;
    #pragma unroll
    for (int off = 32; off; off >>= 1) v += __shfl_xor(v, off, 64);
    __syncthreads();
    if ((tid & 63) == 0) red[tid >> 6] = v;
    __syncthreads();
    const float var = (red[0] + red[1] + red[2] + red[3]) * (1.f / 512.f);
    const float inv = rsqrtf(var + LN_EPS);

    out[(size_t)row * 512 + tid] = d0 * inv * g[tid] + bb[tid];
    out[(size_t)row * 512 + tid + 256] = d1 * inv * g[tid + 256] + bb[tid + 256];
}

// ---------------------------------------------------------------------------
extern "C" void kernel_launch(void* const* d_in, const int* in_sizes, int n_in,
                              void* d_out, int out_size, void* d_ws, size_t ws_size,
                              hipStream_t stream)
{
    const float* h   = (const float*)d_in[0];
    const float* rh  = (const float*)d_in[1];
    // d_in[2] = Wl, d_in[4] = al : unused — sl cancels in softmax
    const float* Wr  = (const float*)d_in[3];
    const float* ar  = (const float*)d_in[5];
    const float* Wrs = (const float*)d_in[6];
    const float* Wrt = (const float*)d_in[7];
    const float* Wf  = (const float*)d_in[8];
    const float* lng = (const float*)d_in[9];
    const float* lnb = (const float*)d_in[10];
    float* out = (float*)d_out;
    char* wsb  = (char*)d_ws;

    const size_t MB = (size_t)1 << 20;
    ushort* hb   = (ushort*)(wsb);               //  8 MB
    ushort* rhb  = (ushort*)(wsb + 8 * MB);      //  1 MB
    ushort* WrT  = (ushort*)(wsb + 9 * MB);      // .5 MB
    ushort* WfT  = (ushort*)(wsb + 9 * MB + 512 * 1024);
    ushort* WrsT = (ushort*)(wsb + 10 * MB);     // 64 KB
    ushort* WrtT = (ushort*)(wsb + 10 * MB + 64 * 1024);
    ushort* frT  = (ushort*)(wsb + 11 * MB);     //  8 MB  [B,H,64,S]
    ushort* rkw  = (ushort*)(wsb + 19 * MB);     //  8 MB  [B,H,S,64]
    ushort* rqw  = (ushort*)(wsb + 27 * MB);     //  8 MB  [B,H,S,64]
    float*  sr   = (float*) (wsb + 35 * MB);     // .25MB  [B,H,S]
    ushort* hsab = (ushort*)(wsb + 36 * MB);     //  8 MB  [B,S,512] bf16
    float*  fh   = (float*) (wsb + 44 * MB);     // 16 MB  [B,S,512] f32

    dim3 blk(256);
    prep<<<dim3(4752), blk, 0, stream>>>(h, rh, Wr, Wf, Wrs, Wrt,
                                         hb, rhb, WrT, WfT, WrsT, WrtT);
    proj<<<dim3(128, 4, 3), blk, 0, stream>>>(hb, rhb, WrT, WrsT, WrtT,
                                              frT, rkw, rqw, sr, ar);
    // attention: 64 q / 128-thread block, 4 independent domains per CU
    attn_mfma<<<dim3(S_ / 64, H_, B_), dim3(128), 0, stream>>>(frT, rkw, rqw, sr, hsab);
    gemm_out<<<dim3(128, 4), blk, 0, stream>>>(hsab, WfT, fh);
    ln_kernel<<<dim3(B_ * S_), blk, 0, stream>>>(h, fh, lng, lnb, out);
}